// Round 12
// baseline (1761.639 us; speedup 1.0000x reference)
//
#include <hip/hip_runtime.h>
#include <hip/hip_bf16.h>

// ---------------------------------------------------------------------------
// PoseFeatureNet R20:
//  - k_gemm_mfma REVERTED to BK=32 (R18 exact; BK=64's 32 KB LDS cost more
//    occupancy than the halved barrier count saved: 974.4 -> 998.1).
//  - k_lstm_f17 = f16 + kc6-7 ALSO in AGPRs: Ba[2][8][4] = 64 frags =
//    256 AGPR + 128 VGPR = 384 regs/thread (cap 512/wave, pool allows
//    ~5 waves/SIMD at 384 -> 2 waves/SIMD trivially fits). Whh now 100%
//    register-resident; Wl LDS staging and its 16 ds_read_b128/wave/step
//    removed; LDS = 4.6 KB. kc order 6,7,0,1,2,3,4,5 preserved ->
//    bit-identical numerics to f16.
//  - everything else byte-identical to R18 (974.4 µs verified).
// ---------------------------------------------------------------------------

#define TT 256
#define BB 128
#define NNODE 17
#define DD 2176    // 17*128
#define LHID 256
#define G4 1024    // 4*LHID
#define NCLS 625

typedef unsigned short u16t;

__device__ __constant__ int ESRC[19] = {15,13,16,14,11,5,6,5,5,6,7,8,1,0,0,1,2,3,4};
__device__ __constant__ int EDST[19] = {13,11,14,12,12,11,12,6,7,8,9,10,2,1,2,3,4,5,6};
__device__ __constant__ float DEGF[17] = {1,2,3,2,2,2,3,2,2,2,2,3,4,2,2,1,1};

__device__ inline float lo2f(unsigned u){ union{unsigned x; float f;} c; c.x = u << 16; return c.f; }
__device__ inline float hi2f(unsigned u){ union{unsigned x; float f;} c; c.x = u & 0xffff0000u; return c.f; }
__device__ inline u16t f2b(float f){
    __hip_bfloat16 h = __float2bfloat16(f);
    u16t s; __builtin_memcpy(&s, &h, 2); return s;
}
__device__ inline float b2f(u16t s){ union{unsigned x; float f;} c; c.x = ((unsigned)s) << 16; return c.f; }
__device__ inline unsigned pack2(float a, float b){
    return (unsigned)f2b(a) | ((unsigned)f2b(b) << 16);
}
__device__ inline float fsig(float x){ return __fdividef(1.f, 1.f + __expf(-x)); }
__device__ inline float ftanh(float x){ float e = __expf(2.f*x); return 1.f - __fdividef(2.f, e + 1.f); }
__device__ inline float sigm(float x){ return 1.f / (1.f + expf(-x)); }

typedef __attribute__((ext_vector_type(8))) short bf16x8;
typedef __attribute__((ext_vector_type(4))) float f32x4;
typedef __attribute__((ext_vector_type(4))) unsigned u32x4;

__device__ inline bf16x8 asB(u32x4 v){ bf16x8 r; __builtin_memcpy(&r, &v, 16); return r; }

__device__ inline void gload16(const void* g, void* l){
    __builtin_amdgcn_global_load_lds(
        (const __attribute__((address_space(1))) void*)g,
        (__attribute__((address_space(3))) void*)l, 16, 0, 0);
}

// --------------------------------------------- W2 -> bf16 transposed [n][k]
__global__ void k_w2t(const float* __restrict__ W2, __hip_bfloat16* __restrict__ W2Tb){
    int g = blockIdx.x * 256 + threadIdx.x;   // 16384
    int k = g >> 7, n = g & 127;
    W2Tb[n * 128 + k] = __float2bfloat16(W2[g]);
}

// --------------------------------------------- Wih_f -> bf16 [n][k] (one-off)
__global__ void k_wb16(const float* __restrict__ W, u16t* __restrict__ Wb){
    int g = blockIdx.x * 256 + threadIdx.x;   // 278,528 threads x 8 elems
    const float4 f0 = *(const float4*)(W + (size_t)g*8);
    const float4 f1 = *(const float4*)(W + (size_t)g*8 + 4);
    uint4 o;
    o.x = pack2(f0.x, f0.y); o.y = pack2(f0.z, f0.w);
    o.z = pack2(f1.x, f1.y); o.w = pack2(f1.z, f1.w);
    *(uint4*)(Wb + (size_t)g*8) = o;
}

// ------------------- Whh -> bf16 fragments, R5 packing (16 waves, nt = gate)
// frag f = w*32 + kc*4 + nt  (w:16 col-tiles, kc:8, nt:4 gates)
// lane l holds B[k = kc*32 + (l>>4)*8 ..+8][col = nt*256 + w*16 + (l&15)]
__global__ void k_wfrag(const float* __restrict__ Whh, __hip_bfloat16* __restrict__ WTfrag){
    int g = blockIdx.x * 256 + threadIdx.x;   // 32768
    int f = g >> 6, lane = g & 63;
    int w = f >> 5, kc = (f >> 2) & 7, nt = f & 3;
    int col = nt*256 + w*16 + (lane & 15);
    int k0  = kc*32 + (lane >> 4)*8;
    const float* src = Whh + (size_t)col * 256 + k0;
    float4 f0 = *(const float4*)src;
    float4 f1 = *(const float4*)(src + 4);
    uint4 o;
    o.x = pack2(f0.x, f0.y); o.y = pack2(f0.z, f0.w);
    o.z = pack2(f1.x, f1.y); o.w = pack2(f1.z, f1.w);
    *(uint4*)((char*)WTfrag + (size_t)g * 16) = o;
}

// ------------------------------------------------------------ fused GCN block
__global__ __launch_bounds__(512) void k_gcnfused(
    const float* __restrict__ pose1, const float* __restrict__ pose2,
    const float* __restrict__ W1, const float* __restrict__ b1,
    const float* __restrict__ b2, const __hip_bfloat16* __restrict__ W2Tb,
    __hip_bfloat16* __restrict__ feats)
{
    __shared__ u16t  Abuf[272][136];
    __shared__ u16t  BsmT[128][136];
    __shared__ float ps4[2][16][17][4];
    __shared__ float araw[17*128];
    __shared__ float araw2[17*128];
    __shared__ float As[289];

    const int tid = threadIdx.x;
    const int blk = blockIdx.x;
    const int t   = blk >> 3;
    const int bc  = blk & 7;

    for (int idx = tid; idx < 1632; idx += 512){
        int p_ = idx >= 816 ? 1 : 0;
        int r  = idx - p_ * 816;
        int bl = r / 51, i = r - bl * 51;
        int n = i / 3, c = i - n * 3;
        const float* src = p_ ? pose2 : pose1;
        ps4[p_][bl][n][c] = src[(size_t)((bc*16 + bl) * TT + t) * 51 + i];
    }
    {
        const uint4* src = (const uint4*)W2Tb;
        for (int r = 0; r < 2; ++r){
            int f0 = (tid + r * 512) * 16;
            int n = f0 >> 7, k0 = f0 & 127;
            uint4 v0 = src[(tid + r*512)*2 + 0];
            uint4 v1 = src[(tid + r*512)*2 + 1];
            *(uint4*)&BsmT[n][k0]     = v0;
            *(uint4*)&BsmT[n][k0 + 8] = v1;
        }
    }
    if (bc == 0 && tid < 289){
        int i = tid / 17, j = tid - (tid/17)*17;
        float a = (i == j) ? 1.0f / DEGF[i] : 0.0f;
        for (int e = 0; e < 19; ++e)
            if (EDST[e] == i && ESRC[e] == j)
                a += 1.0f / sqrtf(DEGF[i] * DEGF[j]);
        As[tid] = a;
    }

    const int h = tid & 127;
    const int q = tid >> 7;
    const float w10 = W1[h], w11 = W1[128 + h], w12 = W1[256 + h];
    const float b1h = b1[h];
    __syncthreads();

    float a2st[5];
    int nl[5], nv = 0;
    for (int s = 0; s < 5; ++s){ int n = q + 4*s; if (n < NNODE) nl[nv++] = n; }
    for (int s = 0; s < nv; ++s){
        int n = nl[s];
        for (int bl = 0; bl < 16; ++bl){
            float4 p1 = *(const float4*)&ps4[0][bl][n][0];
            float4 p2 = *(const float4*)&ps4[1][bl][n][0];
            float a1 = p1.x*w10 + p1.y*w11 + p1.z*w12;
            float a2 = p2.x*w10 + p2.y*w11 + p2.z*w12;
            if (bc == 0 && bl == 0){
                araw[n*128 + h] = a1;
                a2st[s] = a2;
            } else {
                float r1 = fmaxf(a1 + b1h, 0.f);
                float r2 = fmaxf(a2 + b1h, 0.f);
                Abuf[n*16 + bl][h] = f2b(0.5f*(r1 + r2));
            }
        }
    }
    __syncthreads();
    if (bc == 0){
        for (int s = 0; s < nv; ++s){
            int n = nl[s]; float a = 0.f;
            #pragma unroll
            for (int j = 0; j < NNODE; ++j) a += As[n*17 + j] * araw[j*128 + h];
            araw2[n*128 + h] = fmaxf(a + b1h, 0.f);
        }
    }
    __syncthreads();
    if (bc == 0){
        for (int s = 0; s < nv; ++s){
            int n = nl[s]; float a = 0.f;
            #pragma unroll
            for (int j = 0; j < NNODE; ++j) a += As[n*17 + j] * araw2[j*128 + h];
            float r2 = fmaxf(a2st[s] + b1h, 0.f);
            Abuf[n*16 + 0][h] = f2b(0.5f*(a + r2));
        }
    }
    __syncthreads();

    const int w = tid >> 6, l = tid & 63;
    const int l15 = l & 15, q8 = (l >> 4) * 8, q4 = (l >> 4) * 4;
    float bias[8];
    #pragma unroll
    for (int nt = 0; nt < 8; ++nt) bias[nt] = b2[nt*16 + l15];

    bf16x8 Bf[4][8];
    #pragma unroll
    for (int kc = 0; kc < 4; ++kc)
        #pragma unroll
        for (int nt = 0; nt < 8; ++nt)
            Bf[kc][nt] = *(const bf16x8*)&BsmT[nt*16 + l15][kc*32 + q8];

    u16t* Cb = (u16t*)feats;
    for (int mt = w; mt < NNODE; mt += 8){
        f32x4 acc[8];
        #pragma unroll
        for (int nt = 0; nt < 8; ++nt) acc[nt] = (f32x4){0.f,0.f,0.f,0.f};
        #pragma unroll
        for (int kc = 0; kc < 4; ++kc){
            bf16x8 a = *(const bf16x8*)&Abuf[mt*16 + l15][kc*32 + q8];
            #pragma unroll
            for (int nt = 0; nt < 8; ++nt)
                acc[nt] = __builtin_amdgcn_mfma_f32_16x16x32_bf16(a, Bf[kc][nt], acc[nt], 0,0,0);
        }
        #pragma unroll
        for (int nt = 0; nt < 8; ++nt)
            #pragma unroll
            for (int r = 0; r < 4; ++r){
                size_t row = (size_t)(blk*16 + q4 + r) * NNODE + mt;
                Cb[row*128 + nt*16 + l15] = f2b(acc[nt][r] + bias[nt]);
            }
    }
}

// ------------------------------------------------- pre_f GEMM: bf16 MFMA
// R18 exact: BK=32, 1-D grid 2048, XCD-aware swizzle. R5 epilogue layout:
// off = t*131072 + (b>>4)*16384 + (j>>4)*1024 + ((b&15)>>2)*256 + (b&3)*64
//       + (j&15)*4 + gate      where col = gate*256 + j
// If Bb != nullptr, B staged via global_load_lds from prepped bf16;
// else f32-conversion fallback.
__global__ __launch_bounds__(256) void k_gemm_mfma(
    const __hip_bfloat16* __restrict__ A, const float* __restrict__ Bw,
    const u16t* __restrict__ Bb,
    const float* __restrict__ bi1, const float* __restrict__ bi2,
    u16t* __restrict__ pre2)
{
    __shared__ u16t Asm[128][32];
    __shared__ u16t Bsm[128][32];
    const int tid = threadIdx.x;
    const int w = tid >> 6;
    const int l = tid & 63;

    const int blk = blockIdx.x;
    const int xcd = blk & 7;
    const int i_  = blk >> 3;              // 0..255
    const int bx  = xcd * 32 + (i_ >> 3);  // t-panel 0..255
    const int by  = i_ & 7;                // n-panel 0..7

    const size_t m0 = (size_t)bx * 128;
    const int n0 = by * 128;
    const int mw = (w >> 1) * 64;
    const int nw = (w & 1) * 64;

    f32x4 acc[4][4];
    #pragma unroll
    for (int s = 0; s < 4; ++s)
        #pragma unroll
        for (int t_ = 0; t_ < 4; ++t_)
            acc[s][t_] = (f32x4){0.f, 0.f, 0.f, 0.f};

    const u16t* Ab = (const u16t*)A;
    const int arow = w*32 + (l>>2);
    const int akoff = (l&3)*8;
    const int brow = w*32 + (l>>1);
    const int bko  = (l&1)*16;
    const int fr = l & 15, fq = (l >> 4) * 8;

    for (int kt = 0; kt < DD; kt += 32){
        gload16(Ab + (m0 + arow)*DD + kt + akoff,      &Asm[arow][akoff]);
        gload16(Ab + (m0 + arow + 16)*DD + kt + akoff, &Asm[arow+16][akoff]);
        if (Bb){
            gload16(Bb + (size_t)(n0 + arow)*DD + kt + akoff,      &Bsm[arow][akoff]);
            gload16(Bb + (size_t)(n0 + arow + 16)*DD + kt + akoff, &Bsm[arow+16][akoff]);
        } else {
            const float* bp = Bw + (size_t)(n0 + brow)*DD + kt + bko;
            float4 f0 = *(const float4*)bp;
            float4 f1 = *(const float4*)(bp+4);
            float4 f2 = *(const float4*)(bp+8);
            float4 f3 = *(const float4*)(bp+12);
            uint4 o0, o1;
            o0.x = pack2(f0.x,f0.y); o0.y = pack2(f0.z,f0.w);
            o0.z = pack2(f1.x,f1.y); o0.w = pack2(f1.z,f1.w);
            o1.x = pack2(f2.x,f2.y); o1.y = pack2(f2.z,f2.w);
            o1.z = pack2(f3.x,f3.y); o1.w = pack2(f3.z,f3.w);
            *(uint4*)&Bsm[brow][bko]   = o0;
            *(uint4*)&Bsm[brow][bko+8] = o1;
        }
        __syncthreads();

        bf16x8 af[4], bf[4];
        #pragma unroll
        for (int s = 0; s < 4; ++s) af[s] = *(const bf16x8*)&Asm[mw + s*16 + fr][fq];
        #pragma unroll
        for (int t_ = 0; t_ < 4; ++t_) bf[t_] = *(const bf16x8*)&Bsm[nw + t_*16 + fr][fq];
        #pragma unroll
        for (int s = 0; s < 4; ++s)
            #pragma unroll
            for (int t_ = 0; t_ < 4; ++t_)
                acc[s][t_] = __builtin_amdgcn_mfma_f32_16x16x32_bf16(af[s], bf[t_], acc[s][t_], 0, 0, 0);
        __syncthreads();
    }

    const int cr = (l >> 4) * 4;
    const int cc = l & 15;
    const int tIdx = bx;   // rows are t-major: row = t*128 + b
    #pragma unroll
    for (int t_ = 0; t_ < 4; ++t_){
        int col = n0 + nw + t_*16 + cc;
        float bias = bi1[col] + bi2[col];
        int gate = col >> 8;
        int j    = col & 255;
        size_t cbase = (size_t)tIdx*131072 + (size_t)(j>>4)*1024 + (size_t)(j&15)*4 + gate;
        #pragma unroll
        for (int s = 0; s < 4; ++s)
            #pragma unroll
            for (int r = 0; r < 4; ++r){
                int b = mw + s*16 + cr + r;
                pre2[cbase + (size_t)(b>>4)*16384 + ((b&15)>>2)*256 + (b&3)*64]
                    = f2b(acc[s][t_][r] + bias);
            }
    }
}

// --------------------- backward LSTM: one step from zero state (unchanged)
__global__ __launch_bounds__(256) void k_lstm_b(
    const __hip_bfloat16* __restrict__ feats255,
    const float* __restrict__ Wih_b,
    const float* __restrict__ bih_b, const float* __restrict__ bhh_b,
    float* __restrict__ h_b)
{
    __shared__ float fs[DD];
    const int tid = threadIdx.x;
    const int b = blockIdx.x;
    const unsigned* fbu = (const unsigned*)(feats255 + (size_t)b * DD);
    for (int i = tid; i < DD/2; i += 256){
        unsigned u = fbu[i];
        fs[2*i] = lo2f(u); fs[2*i+1] = hi2f(u);
    }
    __syncthreads();

    const int w = tid >> 6, lane = tid & 63;
    const int j = blockIdx.y * 4 + w;
    const float* Wi = Wih_b + (size_t)j * DD;
    const float* Wg = Wih_b + (size_t)(512 + j) * DD;
    const float* Wo = Wih_b + (size_t)(768 + j) * DD;
    float si = 0.f, sg = 0.f, so = 0.f;
    #pragma unroll 2
    for (int i = 0; i < 34; ++i){
        int k = lane + i*64;
        float f = fs[k];
        si += f * Wi[k]; sg += f * Wg[k]; so += f * Wo[k];
    }
    #pragma unroll
    for (int off = 32; off > 0; off >>= 1){
        si += __shfl_down(si, off);
        sg += __shfl_down(sg, off);
        so += __shfl_down(so, off);
    }
    if (lane == 0){
        float zi = si + bih_b[j]       + bhh_b[j];
        float zg = sg + bih_b[512 + j] + bhh_b[512 + j];
        float zo = so + bih_b[768 + j] + bhh_b[768 + j];
        float c = sigm(zi) * tanhf(zg);
        h_b[(size_t)b*LHID + j] = sigm(zo) * tanhf(c);
    }
}

// ------------- forward LSTM R20: 512 thr / 8 waves, Whh 100% in AGPRs.
// 128 WGs x 1 sample. Wave w owns col-tiles {w, w+8} x 4 gates, full K=256.
// ALL kc 0-7 for both tiles in AGPR: 64 frags = 256 AGPR + 128 VGPR =
// 384 regs/thread (<=512/wave cap; 2 waves/SIMD fits the pool). No Wl,
// no LDS B reads; LDS = zbuf+hbuf (4.6 KB). kc order 6,7,0,1,2,3,4,5
// (outer), tile/nt inner -> bit-identical accumulation to f16.
__global__ __launch_bounds__(512, 2) void k_lstm_f17(
    const u16t* __restrict__ pre2,            // R5 permuted layout
    const __hip_bfloat16* __restrict__ WTfrag,
    float* __restrict__ hout)                 // (128,256)
{
    __shared__ __align__(16) float zbuf[256][4];  // 4 KB: z handoff [j][gate]
    __shared__ __align__(16) u16t hbuf[256];      // current h (bf16)

    const int tid = threadIdx.x;                  // 0..511
    const int w = tid >> 6, l = tid & 63;         // w: 0..7
    const int q = l >> 4, l15 = l & 15, q8 = q * 8;
    const int g = blockIdx.x;                     // sample index 0..127
    const u16t* wtf = (const u16t*)WTfrag;

    if (tid < 256) hbuf[tid] = 0;

    // all 8 kc for tiles {w, w+8}: 64 frags = 256 AGPR ("+a"-pinned)
    u32x4 Ba[2][8][4];
    #pragma unroll
    for (int s = 0; s < 2; ++s){
        const int wt = w + s*8;
        #pragma unroll
        for (int kc = 0; kc < 8; ++kc)
            #pragma unroll
            for (int nt = 0; nt < 4; ++nt){
                Ba[s][kc][nt] = *(const u32x4*)(wtf + (((size_t)(wt*32 + kc*4 + nt))*64 + l)*8);
                asm volatile("" : "+a"(Ba[s][kc][nt]));
            }
    }

    // gate-phase state: thread j (< 256) owns column j of this sample
    const int j = tid;
    float cst = 0.f;
    const size_t pj = (size_t)(g >> 4)*16384 + (size_t)((g & 15) >> 2)*256
                    + (size_t)(g & 3)*64 + (size_t)(j >> 4)*1024 + (size_t)(j & 15)*4;
    const u16t* pp = pre2 + pj;
    union { uint2 v; u16t s4[4]; } prc, prn;
    if (tid < 256) prc.v = *(const uint2*)pp;   // t = 0
    __syncthreads();

    #pragma unroll 1
    for (int t = 0; t < TT; ++t){
        // prefetch next step's pre (consumed after next barrier pair)
        if (tid < 256){
            int tn = (t + 1 < TT) ? t + 1 : t;
            prn.v = *(const uint2*)(pp + (size_t)tn*131072);
        }

        f32x4 acc[2][4];
        #pragma unroll
        for (int s = 0; s < 2; ++s)
            #pragma unroll
            for (int nt = 0; nt < 4; ++nt) acc[s][nt] = (f32x4){0.f,0.f,0.f,0.f};

        // kc6-7 first (same order as f16), then kc0-5; all B from AGPR
        #pragma unroll
        for (int kc = 6; kc < 8; ++kc){
            bf16x8 ah = *(const bf16x8*)&hbuf[kc*32 + q8];
            #pragma unroll
            for (int s = 0; s < 2; ++s)
                #pragma unroll
                for (int nt = 0; nt < 4; ++nt)
                    acc[s][nt] = __builtin_amdgcn_mfma_f32_16x16x32_bf16(ah, asB(Ba[s][kc][nt]), acc[s][nt], 0,0,0);
        }
        #pragma unroll
        for (int kc = 0; kc < 6; ++kc){
            bf16x8 ah = *(const bf16x8*)&hbuf[kc*32 + q8];   // broadcast per q-group
            #pragma unroll
            for (int s = 0; s < 2; ++s)
                #pragma unroll
                for (int nt = 0; nt < 4; ++nt)
                    acc[s][nt] = __builtin_amdgcn_mfma_f32_16x16x32_bf16(ah, asB(Ba[s][kc][nt]), acc[s][nt], 0,0,0);
        }

        // hand off row-0 z values: lanes q==0 hold D[row 0][col wt*16+l15]
        if (q == 0){
            float4 z0, z1;
            z0.x = acc[0][0][0]; z0.y = acc[0][1][0]; z0.z = acc[0][2][0]; z0.w = acc[0][3][0];
            z1.x = acc[1][0][0]; z1.y = acc[1][1][0]; z1.z = acc[1][2][0]; z1.w = acc[1][3][0];
            *(float4*)&zbuf[w*16 + l15][0]       = z0;
            *(float4*)&zbuf[(w+8)*16 + l15][0]   = z1;
        }
        __syncthreads();

        // gate phase: waves 0-3 (one per SIMD), one h column per thread
        if (tid < 256){
            float4 z = *(const float4*)&zbuf[j][0];
            float zi = z.x + b2f(prc.s4[0]);
            float zf = z.y + b2f(prc.s4[1]);
            float zg = z.z + b2f(prc.s4[2]);
            float zo = z.w + b2f(prc.s4[3]);
            float cn = fsig(zf)*cst + fsig(zi)*ftanh(zg);
            cst = cn;
            float hh = fsig(zo)*ftanh(cn);
            if (t < TT - 1)
                hbuf[j] = f2b(hh);
            else
                hout[(size_t)g*LHID + j] = hh;
        }
        prc = prn;
        __syncthreads();   // h handoff: hbuf[j] visible before next MFMA phase
    }
}

// ----------------------------------------------------- head (unchanged)
__global__ __launch_bounds__(256) void k_head(
    const float* __restrict__ h_f, const float* __restrict__ h_b,
    const float* __restrict__ Wc, const float* __restrict__ bc,
    float* __restrict__ out)
{
    __shared__ float pool[512];
    const int b = blockIdx.x, tid = threadIdx.x;
    float p0 = fmaxf(h_f[(size_t)b*LHID + tid], 0.f);
    float p1 = fmaxf(h_b[(size_t)b*LHID + tid], 0.f);
    pool[tid] = p0; pool[256 + tid] = p1;
    out[(size_t)b*512 + tid]       = p0;
    out[(size_t)b*512 + 256 + tid] = p1;
    __syncthreads();
    for (int n = tid; n < NCLS; n += 256){
        float a = bc[n];
        const float* ww = Wc + (size_t)n * 512;
        #pragma unroll 4
        for (int k = 0; k < 512; k += 4){
            float4 wv = *(const float4*)(ww + k);
            a += pool[k]*wv.x + pool[k+1]*wv.y + pool[k+2]*wv.z + pool[k+3]*wv.w;
        }
        out[(size_t)BB*512 + (size_t)b*NCLS + n] = a;
    }
}

// ---------------------------------------------------------------------------
extern "C" void kernel_launch(void* const* d_in, const int* in_sizes, int n_in,
                              void* d_out, int out_size, void* d_ws, size_t ws_size,
                              hipStream_t stream) {
    const float* pose1 = (const float*)d_in[0];
    const float* pose2 = (const float*)d_in[1];
    const float* W1    = (const float*)d_in[2];
    const float* b1    = (const float*)d_in[3];
    const float* W2    = (const float*)d_in[4];
    const float* b2    = (const float*)d_in[5];
    const float* Wih_f = (const float*)d_in[6];
    const float* Whh_f = (const float*)d_in[7];
    const float* bih_f = (const float*)d_in[8];
    const float* bhh_f = (const float*)d_in[9];
    const float* Wih_b = (const float*)d_in[10];
    const float* bih_b = (const float*)d_in[12];
    const float* bhh_b = (const float*)d_in[13];
    const float* Wc    = (const float*)d_in[14];
    const float* bc    = (const float*)d_in[15];
    (void)in_sizes; (void)n_in; (void)out_size;
    float* out = (float*)d_out;
    char* ws = (char*)d_ws;

    // base workspace footprint 211,812,352 B (R12 layout)
    __hip_bfloat16* WTfrag = (__hip_bfloat16*)(ws + 0);           // 524,288
    __hip_bfloat16* W2Tb   = (__hip_bfloat16*)(ws + 524288);      //  32,768
    float*          h_b    = (float*)(ws + 557056);               // 131,072
    float*          h_f    = (float*)(ws + 688128);               // 131,072
    __hip_bfloat16* feats  = (__hip_bfloat16*)(ws + 2097152);     // 142,606,336
    u16t*           pre2   = (u16t*)(ws + 144703488);             //  67,108,864

    // optional bf16 copy of Wih_f (4,456,448 B) -- only if ws has headroom
    const size_t BASE = 211812352, WBSZ = 4456448;
    const bool haveWb = (ws_size >= BASE + WBSZ);
    u16t* Wb16 = haveWb ? (u16t*)(ws + BASE) : (u16t*)nullptr;

    k_w2t     <<<64, 256, 0, stream>>>(W2, W2Tb);
    k_wfrag   <<<128, 256, 0, stream>>>(Whh_f, WTfrag);
    if (haveWb)
        k_wb16<<<1088, 256, 0, stream>>>(Wih_f, Wb16);
    k_gcnfused<<<2048, 512, 0, stream>>>(pose1, pose2, W1, b1, b2, W2Tb, feats);
    k_gemm_mfma<<<2048, 256, 0, stream>>>(feats, Wih_f, Wb16, bih_f, bhh_f, pre2);
    k_lstm_b  <<<dim3(128, 64), 256, 0, stream>>>(feats + (size_t)255*BB*DD, Wih_b, bih_b, bhh_b, h_b);
    k_lstm_f17<<<128, 512, 0, stream>>>(pre2, WTfrag, h_f);
    k_head    <<<128, 256, 0, stream>>>(h_f, h_b, Wc, bc, out);
}

// Round 13
// 966.921 us; speedup vs baseline: 1.8219x; 1.8219x over previous
//
#include <hip/hip_runtime.h>
#include <hip/hip_bf16.h>

// ---------------------------------------------------------------------------
// PoseFeatureNet R21 = R18 exact (974.4 µs verified best).
//  - k_lstm_f17 REVERTED to f16: 256 AGPR ("+a" x64 quads) saturated the
//    AGPR class -> allocator temps spilled to scratch (WRITE_SIZE 1.6->18.6
//    MB, dur 492->1280). AGPR pin budget boundary: 192 works, 256 spills.
//    f16's kc0-5-AGPR / kc6-7-LDS partition is the optimum of this axis
//    (f17 also showed LDS-B reads were fully hidden -> no upside anyway).
//  - gemm BK=32 (BK=64 regressed: LDS occupancy), bf16-B gload_lds staging,
//    XCD swizzle, R5-permuted pre2 (read-side-owned layout).
// ---------------------------------------------------------------------------

#define TT 256
#define BB 128
#define NNODE 17
#define DD 2176    // 17*128
#define LHID 256
#define G4 1024    // 4*LHID
#define NCLS 625

typedef unsigned short u16t;

__device__ __constant__ int ESRC[19] = {15,13,16,14,11,5,6,5,5,6,7,8,1,0,0,1,2,3,4};
__device__ __constant__ int EDST[19] = {13,11,14,12,12,11,12,6,7,8,9,10,2,1,2,3,4,5,6};
__device__ __constant__ float DEGF[17] = {1,2,3,2,2,2,3,2,2,2,2,3,4,2,2,1,1};

__device__ inline float lo2f(unsigned u){ union{unsigned x; float f;} c; c.x = u << 16; return c.f; }
__device__ inline float hi2f(unsigned u){ union{unsigned x; float f;} c; c.x = u & 0xffff0000u; return c.f; }
__device__ inline u16t f2b(float f){
    __hip_bfloat16 h = __float2bfloat16(f);
    u16t s; __builtin_memcpy(&s, &h, 2); return s;
}
__device__ inline float b2f(u16t s){ union{unsigned x; float f;} c; c.x = ((unsigned)s) << 16; return c.f; }
__device__ inline unsigned pack2(float a, float b){
    return (unsigned)f2b(a) | ((unsigned)f2b(b) << 16);
}
__device__ inline float fsig(float x){ return __fdividef(1.f, 1.f + __expf(-x)); }
__device__ inline float ftanh(float x){ float e = __expf(2.f*x); return 1.f - __fdividef(2.f, e + 1.f); }
__device__ inline float sigm(float x){ return 1.f / (1.f + expf(-x)); }

typedef __attribute__((ext_vector_type(8))) short bf16x8;
typedef __attribute__((ext_vector_type(4))) float f32x4;
typedef __attribute__((ext_vector_type(4))) unsigned u32x4;

__device__ inline bf16x8 asB(u32x4 v){ bf16x8 r; __builtin_memcpy(&r, &v, 16); return r; }

__device__ inline void gload16(const void* g, void* l){
    __builtin_amdgcn_global_load_lds(
        (const __attribute__((address_space(1))) void*)g,
        (__attribute__((address_space(3))) void*)l, 16, 0, 0);
}

// --------------------------------------------- W2 -> bf16 transposed [n][k]
__global__ void k_w2t(const float* __restrict__ W2, __hip_bfloat16* __restrict__ W2Tb){
    int g = blockIdx.x * 256 + threadIdx.x;   // 16384
    int k = g >> 7, n = g & 127;
    W2Tb[n * 128 + k] = __float2bfloat16(W2[g]);
}

// --------------------------------------------- Wih_f -> bf16 [n][k] (one-off)
__global__ void k_wb16(const float* __restrict__ W, u16t* __restrict__ Wb){
    int g = blockIdx.x * 256 + threadIdx.x;   // 278,528 threads x 8 elems
    const float4 f0 = *(const float4*)(W + (size_t)g*8);
    const float4 f1 = *(const float4*)(W + (size_t)g*8 + 4);
    uint4 o;
    o.x = pack2(f0.x, f0.y); o.y = pack2(f0.z, f0.w);
    o.z = pack2(f1.x, f1.y); o.w = pack2(f1.z, f1.w);
    *(uint4*)(Wb + (size_t)g*8) = o;
}

// ------------------- Whh -> bf16 fragments, R5 packing (16 waves, nt = gate)
// frag f = w*32 + kc*4 + nt  (w:16 col-tiles, kc:8, nt:4 gates)
// lane l holds B[k = kc*32 + (l>>4)*8 ..+8][col = nt*256 + w*16 + (l&15)]
__global__ void k_wfrag(const float* __restrict__ Whh, __hip_bfloat16* __restrict__ WTfrag){
    int g = blockIdx.x * 256 + threadIdx.x;   // 32768
    int f = g >> 6, lane = g & 63;
    int w = f >> 5, kc = (f >> 2) & 7, nt = f & 3;
    int col = nt*256 + w*16 + (lane & 15);
    int k0  = kc*32 + (lane >> 4)*8;
    const float* src = Whh + (size_t)col * 256 + k0;
    float4 f0 = *(const float4*)src;
    float4 f1 = *(const float4*)(src + 4);
    uint4 o;
    o.x = pack2(f0.x, f0.y); o.y = pack2(f0.z, f0.w);
    o.z = pack2(f1.x, f1.y); o.w = pack2(f1.z, f1.w);
    *(uint4*)((char*)WTfrag + (size_t)g * 16) = o;
}

// ------------------------------------------------------------ fused GCN block
__global__ __launch_bounds__(512) void k_gcnfused(
    const float* __restrict__ pose1, const float* __restrict__ pose2,
    const float* __restrict__ W1, const float* __restrict__ b1,
    const float* __restrict__ b2, const __hip_bfloat16* __restrict__ W2Tb,
    __hip_bfloat16* __restrict__ feats)
{
    __shared__ u16t  Abuf[272][136];
    __shared__ u16t  BsmT[128][136];
    __shared__ float ps4[2][16][17][4];
    __shared__ float araw[17*128];
    __shared__ float araw2[17*128];
    __shared__ float As[289];

    const int tid = threadIdx.x;
    const int blk = blockIdx.x;
    const int t   = blk >> 3;
    const int bc  = blk & 7;

    for (int idx = tid; idx < 1632; idx += 512){
        int p_ = idx >= 816 ? 1 : 0;
        int r  = idx - p_ * 816;
        int bl = r / 51, i = r - bl * 51;
        int n = i / 3, c = i - n * 3;
        const float* src = p_ ? pose2 : pose1;
        ps4[p_][bl][n][c] = src[(size_t)((bc*16 + bl) * TT + t) * 51 + i];
    }
    {
        const uint4* src = (const uint4*)W2Tb;
        for (int r = 0; r < 2; ++r){
            int f0 = (tid + r * 512) * 16;
            int n = f0 >> 7, k0 = f0 & 127;
            uint4 v0 = src[(tid + r*512)*2 + 0];
            uint4 v1 = src[(tid + r*512)*2 + 1];
            *(uint4*)&BsmT[n][k0]     = v0;
            *(uint4*)&BsmT[n][k0 + 8] = v1;
        }
    }
    if (bc == 0 && tid < 289){
        int i = tid / 17, j = tid - (tid/17)*17;
        float a = (i == j) ? 1.0f / DEGF[i] : 0.0f;
        for (int e = 0; e < 19; ++e)
            if (EDST[e] == i && ESRC[e] == j)
                a += 1.0f / sqrtf(DEGF[i] * DEGF[j]);
        As[tid] = a;
    }

    const int h = tid & 127;
    const int q = tid >> 7;
    const float w10 = W1[h], w11 = W1[128 + h], w12 = W1[256 + h];
    const float b1h = b1[h];
    __syncthreads();

    float a2st[5];
    int nl[5], nv = 0;
    for (int s = 0; s < 5; ++s){ int n = q + 4*s; if (n < NNODE) nl[nv++] = n; }
    for (int s = 0; s < nv; ++s){
        int n = nl[s];
        for (int bl = 0; bl < 16; ++bl){
            float4 p1 = *(const float4*)&ps4[0][bl][n][0];
            float4 p2 = *(const float4*)&ps4[1][bl][n][0];
            float a1 = p1.x*w10 + p1.y*w11 + p1.z*w12;
            float a2 = p2.x*w10 + p2.y*w11 + p2.z*w12;
            if (bc == 0 && bl == 0){
                araw[n*128 + h] = a1;
                a2st[s] = a2;
            } else {
                float r1 = fmaxf(a1 + b1h, 0.f);
                float r2 = fmaxf(a2 + b1h, 0.f);
                Abuf[n*16 + bl][h] = f2b(0.5f*(r1 + r2));
            }
        }
    }
    __syncthreads();
    if (bc == 0){
        for (int s = 0; s < nv; ++s){
            int n = nl[s]; float a = 0.f;
            #pragma unroll
            for (int j = 0; j < NNODE; ++j) a += As[n*17 + j] * araw[j*128 + h];
            araw2[n*128 + h] = fmaxf(a + b1h, 0.f);
        }
    }
    __syncthreads();
    if (bc == 0){
        for (int s = 0; s < nv; ++s){
            int n = nl[s]; float a = 0.f;
            #pragma unroll
            for (int j = 0; j < NNODE; ++j) a += As[n*17 + j] * araw2[j*128 + h];
            float r2 = fmaxf(a2st[s] + b1h, 0.f);
            Abuf[n*16 + 0][h] = f2b(0.5f*(a + r2));
        }
    }
    __syncthreads();

    const int w = tid >> 6, l = tid & 63;
    const int l15 = l & 15, q8 = (l >> 4) * 8, q4 = (l >> 4) * 4;
    float bias[8];
    #pragma unroll
    for (int nt = 0; nt < 8; ++nt) bias[nt] = b2[nt*16 + l15];

    bf16x8 Bf[4][8];
    #pragma unroll
    for (int kc = 0; kc < 4; ++kc)
        #pragma unroll
        for (int nt = 0; nt < 8; ++nt)
            Bf[kc][nt] = *(const bf16x8*)&BsmT[nt*16 + l15][kc*32 + q8];

    u16t* Cb = (u16t*)feats;
    for (int mt = w; mt < NNODE; mt += 8){
        f32x4 acc[8];
        #pragma unroll
        for (int nt = 0; nt < 8; ++nt) acc[nt] = (f32x4){0.f,0.f,0.f,0.f};
        #pragma unroll
        for (int kc = 0; kc < 4; ++kc){
            bf16x8 a = *(const bf16x8*)&Abuf[mt*16 + l15][kc*32 + q8];
            #pragma unroll
            for (int nt = 0; nt < 8; ++nt)
                acc[nt] = __builtin_amdgcn_mfma_f32_16x16x32_bf16(a, Bf[kc][nt], acc[nt], 0,0,0);
        }
        #pragma unroll
        for (int nt = 0; nt < 8; ++nt)
            #pragma unroll
            for (int r = 0; r < 4; ++r){
                size_t row = (size_t)(blk*16 + q4 + r) * NNODE + mt;
                Cb[row*128 + nt*16 + l15] = f2b(acc[nt][r] + bias[nt]);
            }
    }
}

// ------------------------------------------------- pre_f GEMM: bf16 MFMA
// R18 exact: BK=32, 1-D grid 2048, XCD-aware swizzle. R5 epilogue layout:
// off = t*131072 + (b>>4)*16384 + (j>>4)*1024 + ((b&15)>>2)*256 + (b&3)*64
//       + (j&15)*4 + gate      where col = gate*256 + j
// If Bb != nullptr, B staged via global_load_lds from prepped bf16;
// else f32-conversion fallback.
__global__ __launch_bounds__(256) void k_gemm_mfma(
    const __hip_bfloat16* __restrict__ A, const float* __restrict__ Bw,
    const u16t* __restrict__ Bb,
    const float* __restrict__ bi1, const float* __restrict__ bi2,
    u16t* __restrict__ pre2)
{
    __shared__ u16t Asm[128][32];
    __shared__ u16t Bsm[128][32];
    const int tid = threadIdx.x;
    const int w = tid >> 6;
    const int l = tid & 63;

    const int blk = blockIdx.x;
    const int xcd = blk & 7;
    const int i_  = blk >> 3;              // 0..255
    const int bx  = xcd * 32 + (i_ >> 3);  // t-panel 0..255
    const int by  = i_ & 7;                // n-panel 0..7

    const size_t m0 = (size_t)bx * 128;
    const int n0 = by * 128;
    const int mw = (w >> 1) * 64;
    const int nw = (w & 1) * 64;

    f32x4 acc[4][4];
    #pragma unroll
    for (int s = 0; s < 4; ++s)
        #pragma unroll
        for (int t_ = 0; t_ < 4; ++t_)
            acc[s][t_] = (f32x4){0.f, 0.f, 0.f, 0.f};

    const u16t* Ab = (const u16t*)A;
    const int arow = w*32 + (l>>2);
    const int akoff = (l&3)*8;
    const int brow = w*32 + (l>>1);
    const int bko  = (l&1)*16;
    const int fr = l & 15, fq = (l >> 4) * 8;

    for (int kt = 0; kt < DD; kt += 32){
        gload16(Ab + (m0 + arow)*DD + kt + akoff,      &Asm[arow][akoff]);
        gload16(Ab + (m0 + arow + 16)*DD + kt + akoff, &Asm[arow+16][akoff]);
        if (Bb){
            gload16(Bb + (size_t)(n0 + arow)*DD + kt + akoff,      &Bsm[arow][akoff]);
            gload16(Bb + (size_t)(n0 + arow + 16)*DD + kt + akoff, &Bsm[arow+16][akoff]);
        } else {
            const float* bp = Bw + (size_t)(n0 + brow)*DD + kt + bko;
            float4 f0 = *(const float4*)bp;
            float4 f1 = *(const float4*)(bp+4);
            float4 f2 = *(const float4*)(bp+8);
            float4 f3 = *(const float4*)(bp+12);
            uint4 o0, o1;
            o0.x = pack2(f0.x,f0.y); o0.y = pack2(f0.z,f0.w);
            o0.z = pack2(f1.x,f1.y); o0.w = pack2(f1.z,f1.w);
            o1.x = pack2(f2.x,f2.y); o1.y = pack2(f2.z,f2.w);
            o1.z = pack2(f3.x,f3.y); o1.w = pack2(f3.z,f3.w);
            *(uint4*)&Bsm[brow][bko]   = o0;
            *(uint4*)&Bsm[brow][bko+8] = o1;
        }
        __syncthreads();

        bf16x8 af[4], bf[4];
        #pragma unroll
        for (int s = 0; s < 4; ++s) af[s] = *(const bf16x8*)&Asm[mw + s*16 + fr][fq];
        #pragma unroll
        for (int t_ = 0; t_ < 4; ++t_) bf[t_] = *(const bf16x8*)&Bsm[nw + t_*16 + fr][fq];
        #pragma unroll
        for (int s = 0; s < 4; ++s)
            #pragma unroll
            for (int t_ = 0; t_ < 4; ++t_)
                acc[s][t_] = __builtin_amdgcn_mfma_f32_16x16x32_bf16(af[s], bf[t_], acc[s][t_], 0, 0, 0);
        __syncthreads();
    }

    const int cr = (l >> 4) * 4;
    const int cc = l & 15;
    const int tIdx = bx;   // rows are t-major: row = t*128 + b
    #pragma unroll
    for (int t_ = 0; t_ < 4; ++t_){
        int col = n0 + nw + t_*16 + cc;
        float bias = bi1[col] + bi2[col];
        int gate = col >> 8;
        int j    = col & 255;
        size_t cbase = (size_t)tIdx*131072 + (size_t)(j>>4)*1024 + (size_t)(j&15)*4 + gate;
        #pragma unroll
        for (int s = 0; s < 4; ++s)
            #pragma unroll
            for (int r = 0; r < 4; ++r){
                int b = mw + s*16 + cr + r;
                pre2[cbase + (size_t)(b>>4)*16384 + ((b&15)>>2)*256 + (b&3)*64]
                    = f2b(acc[s][t_][r] + bias);
            }
    }
}

// --------------------- backward LSTM: one step from zero state (unchanged)
__global__ __launch_bounds__(256) void k_lstm_b(
    const __hip_bfloat16* __restrict__ feats255,
    const float* __restrict__ Wih_b,
    const float* __restrict__ bih_b, const float* __restrict__ bhh_b,
    float* __restrict__ h_b)
{
    __shared__ float fs[DD];
    const int tid = threadIdx.x;
    const int b = blockIdx.x;
    const unsigned* fbu = (const unsigned*)(feats255 + (size_t)b * DD);
    for (int i = tid; i < DD/2; i += 256){
        unsigned u = fbu[i];
        fs[2*i] = lo2f(u); fs[2*i+1] = hi2f(u);
    }
    __syncthreads();

    const int w = tid >> 6, lane = tid & 63;
    const int j = blockIdx.y * 4 + w;
    const float* Wi = Wih_b + (size_t)j * DD;
    const float* Wg = Wih_b + (size_t)(512 + j) * DD;
    const float* Wo = Wih_b + (size_t)(768 + j) * DD;
    float si = 0.f, sg = 0.f, so = 0.f;
    #pragma unroll 2
    for (int i = 0; i < 34; ++i){
        int k = lane + i*64;
        float f = fs[k];
        si += f * Wi[k]; sg += f * Wg[k]; so += f * Wo[k];
    }
    #pragma unroll
    for (int off = 32; off > 0; off >>= 1){
        si += __shfl_down(si, off);
        sg += __shfl_down(sg, off);
        so += __shfl_down(so, off);
    }
    if (lane == 0){
        float zi = si + bih_b[j]       + bhh_b[j];
        float zg = sg + bih_b[512 + j] + bhh_b[512 + j];
        float zo = so + bih_b[768 + j] + bhh_b[768 + j];
        float c = sigm(zi) * tanhf(zg);
        h_b[(size_t)b*LHID + j] = sigm(zo) * tanhf(c);
    }
}

// ------------- forward LSTM R18 (FROZEN): 512 thr / 8 waves.
// 128 WGs x 1 sample. Wave w owns col-tiles {w, w+8} x 4 gates, full K=256.
// kc0-5 both tiles in AGPR (192 regs — the verified max; 256 spills),
// kc6-7 in LDS. kc order 6,7,0,1,2,3,4,5 (outer), tile/nt inner.
// Gates: waves 0-3, 2 barriers/step.
__global__ __launch_bounds__(512, 2) void k_lstm_f16(
    const u16t* __restrict__ pre2,            // R5 permuted layout
    const __hip_bfloat16* __restrict__ WTfrag,
    float* __restrict__ hout)                 // (128,256)
{
    __shared__ u16t Wl[65536];                    // 128 KB: kc6-7 frags (16 tiles)
    __shared__ __align__(16) float zbuf[256][4];  // 4 KB: z handoff [j][gate]
    __shared__ __align__(16) u16t hbuf[256];      // current h (bf16)

    const int tid = threadIdx.x;                  // 0..511
    const int w = tid >> 6, l = tid & 63;         // w: 0..7
    const int q = l >> 4, l15 = l & 15, q8 = q * 8;
    const int g = blockIdx.x;                     // sample index 0..127
    const u16t* wtf = (const u16t*)WTfrag;

    // stage kc6-7 fragments into LDS (8192 uint4, 512 threads -> 16 iters)
    {
        const uint4* srcq = (const uint4*)wtf;
        uint4* dstq = (uint4*)Wl;
        for (int i = tid; i < 8192; i += 512){
            int iw = i >> 9, fi = (i >> 6) & 7, il = i & 63;
            dstq[i] = srcq[(iw*32 + 24 + fi)*64 + il];
        }
    }
    if (tid < 256) hbuf[tid] = 0;

    // kc0-5 for tiles {w, w+8}: 48 frags = 192 AGPR ("+a"-pinned)
    u32x4 Ba[2][6][4];
    #pragma unroll
    for (int s = 0; s < 2; ++s){
        const int wt = w + s*8;
        #pragma unroll
        for (int kc = 0; kc < 6; ++kc)
            #pragma unroll
            for (int nt = 0; nt < 4; ++nt){
                Ba[s][kc][nt] = *(const u32x4*)(wtf + (((size_t)(wt*32 + kc*4 + nt))*64 + l)*8);
                asm volatile("" : "+a"(Ba[s][kc][nt]));
            }
    }

    // gate-phase state: thread j (< 256) owns column j of this sample
    const int j = tid;
    float cst = 0.f;
    const size_t pj = (size_t)(g >> 4)*16384 + (size_t)((g & 15) >> 2)*256
                    + (size_t)(g & 3)*64 + (size_t)(j >> 4)*1024 + (size_t)(j & 15)*4;
    const u16t* pp = pre2 + pj;
    union { uint2 v; u16t s4[4]; } prc, prn;
    if (tid < 256) prc.v = *(const uint2*)pp;   // t = 0
    __syncthreads();

    #pragma unroll 1
    for (int t = 0; t < TT; ++t){
        // prefetch next step's pre (consumed after next barrier pair)
        if (tid < 256){
            int tn = (t + 1 < TT) ? t + 1 : t;
            prn.v = *(const uint2*)(pp + (size_t)tn*131072);
        }

        f32x4 acc[2][4];
        #pragma unroll
        for (int s = 0; s < 2; ++s)
            #pragma unroll
            for (int nt = 0; nt < 4; ++nt) acc[s][nt] = (f32x4){0.f,0.f,0.f,0.f};

        // kc6-7 first (LDS B), both tiles share ah
        #pragma unroll
        for (int kc = 6; kc < 8; ++kc){
            bf16x8 ah = *(const bf16x8*)&hbuf[kc*32 + q8];
            #pragma unroll
            for (int s = 0; s < 2; ++s){
                const int wt = w + s*8;
                #pragma unroll
                for (int nt = 0; nt < 4; ++nt){
                    bf16x8 bL = *(const bf16x8*)&Wl[((wt*8 + (kc-6)*4 + nt)*64 + l)*8];
                    acc[s][nt] = __builtin_amdgcn_mfma_f32_16x16x32_bf16(ah, bL, acc[s][nt], 0,0,0);
                }
            }
        }
        // kc0-5 (AGPR-resident B)
        #pragma unroll
        for (int kc = 0; kc < 6; ++kc){
            bf16x8 ah = *(const bf16x8*)&hbuf[kc*32 + q8];   // broadcast per q-group
            #pragma unroll
            for (int s = 0; s < 2; ++s)
                #pragma unroll
                for (int nt = 0; nt < 4; ++nt)
                    acc[s][nt] = __builtin_amdgcn_mfma_f32_16x16x32_bf16(ah, asB(Ba[s][kc][nt]), acc[s][nt], 0,0,0);
        }

        // hand off row-0 z values: lanes q==0 hold D[row 0][col wt*16+l15]
        if (q == 0){
            float4 z0, z1;
            z0.x = acc[0][0][0]; z0.y = acc[0][1][0]; z0.z = acc[0][2][0]; z0.w = acc[0][3][0];
            z1.x = acc[1][0][0]; z1.y = acc[1][1][0]; z1.z = acc[1][2][0]; z1.w = acc[1][3][0];
            *(float4*)&zbuf[w*16 + l15][0]       = z0;
            *(float4*)&zbuf[(w+8)*16 + l15][0]   = z1;
        }
        __syncthreads();

        // gate phase: waves 0-3 (one per SIMD), one h column per thread
        if (tid < 256){
            float4 z = *(const float4*)&zbuf[j][0];
            float zi = z.x + b2f(prc.s4[0]);
            float zf = z.y + b2f(prc.s4[1]);
            float zg = z.z + b2f(prc.s4[2]);
            float zo = z.w + b2f(prc.s4[3]);
            float cn = fsig(zf)*cst + fsig(zi)*ftanh(zg);
            cst = cn;
            float hh = fsig(zo)*ftanh(cn);
            if (t < TT - 1)
                hbuf[j] = f2b(hh);
            else
                hout[(size_t)g*LHID + j] = hh;
        }
        prc = prn;
        __syncthreads();   // h handoff: hbuf[j] visible before next MFMA phase
    }
}

// ----------------------------------------------------- head (unchanged)
__global__ __launch_bounds__(256) void k_head(
    const float* __restrict__ h_f, const float* __restrict__ h_b,
    const float* __restrict__ Wc, const float* __restrict__ bc,
    float* __restrict__ out)
{
    __shared__ float pool[512];
    const int b = blockIdx.x, tid = threadIdx.x;
    float p0 = fmaxf(h_f[(size_t)b*LHID + tid], 0.f);
    float p1 = fmaxf(h_b[(size_t)b*LHID + tid], 0.f);
    pool[tid] = p0; pool[256 + tid] = p1;
    out[(size_t)b*512 + tid]       = p0;
    out[(size_t)b*512 + 256 + tid] = p1;
    __syncthreads();
    for (int n = tid; n < NCLS; n += 256){
        float a = bc[n];
        const float* ww = Wc + (size_t)n * 512;
        #pragma unroll 4
        for (int k = 0; k < 512; k += 4){
            float4 wv = *(const float4*)(ww + k);
            a += pool[k]*wv.x + pool[k+1]*wv.y + pool[k+2]*wv.z + pool[k+3]*wv.w;
        }
        out[(size_t)BB*512 + (size_t)b*NCLS + n] = a;
    }
}

// ---------------------------------------------------------------------------
extern "C" void kernel_launch(void* const* d_in, const int* in_sizes, int n_in,
                              void* d_out, int out_size, void* d_ws, size_t ws_size,
                              hipStream_t stream) {
    const float* pose1 = (const float*)d_in[0];
    const float* pose2 = (const float*)d_in[1];
    const float* W1    = (const float*)d_in[2];
    const float* b1    = (const float*)d_in[3];
    const float* W2    = (const float*)d_in[4];
    const float* b2    = (const float*)d_in[5];
    const float* Wih_f = (const float*)d_in[6];
    const float* Whh_f = (const float*)d_in[7];
    const float* bih_f = (const float*)d_in[8];
    const float* bhh_f = (const float*)d_in[9];
    const float* Wih_b = (const float*)d_in[10];
    const float* bih_b = (const float*)d_in[12];
    const float* bhh_b = (const float*)d_in[13];
    const float* Wc    = (const float*)d_in[14];
    const float* bc    = (const float*)d_in[15];
    (void)in_sizes; (void)n_in; (void)out_size;
    float* out = (float*)d_out;
    char* ws = (char*)d_ws;

    // base workspace footprint 211,812,352 B (R12 layout)
    __hip_bfloat16* WTfrag = (__hip_bfloat16*)(ws + 0);           // 524,288
    __hip_bfloat16* W2Tb   = (__hip_bfloat16*)(ws + 524288);      //  32,768
    float*          h_b    = (float*)(ws + 557056);               // 131,072
    float*          h_f    = (float*)(ws + 688128);               // 131,072
    __hip_bfloat16* feats  = (__hip_bfloat16*)(ws + 2097152);     // 142,606,336
    u16t*           pre2   = (u16t*)(ws + 144703488);             //  67,108,864

    // optional bf16 copy of Wih_f (4,456,448 B) -- only if ws has headroom
    const size_t BASE = 211812352, WBSZ = 4456448;
    const bool haveWb = (ws_size >= BASE + WBSZ);
    u16t* Wb16 = haveWb ? (u16t*)(ws + BASE) : (u16t*)nullptr;

    k_w2t     <<<64, 256, 0, stream>>>(W2, W2Tb);
    k_wfrag   <<<128, 256, 0, stream>>>(Whh_f, WTfrag);
    if (haveWb)
        k_wb16<<<1088, 256, 0, stream>>>(Wih_f, Wb16);
    k_gcnfused<<<2048, 512, 0, stream>>>(pose1, pose2, W1, b1, b2, W2Tb, feats);
    k_gemm_mfma<<<2048, 256, 0, stream>>>(feats, Wih_f, Wb16, bih_f, bhh_f, pre2);
    k_lstm_b  <<<dim3(128, 64), 256, 0, stream>>>(feats + (size_t)255*BB*DD, Wih_b, bih_b, bhh_b, h_b);
    k_lstm_f16<<<128, 512, 0, stream>>>(pre2, WTfrag, h_f);
    k_head    <<<128, 256, 0, stream>>>(h_f, h_b, Wc, bc, out);
}